// Round 1
// baseline (248.134 us; speedup 1.0000x reference)
//
#include <hip/hip_runtime.h>
#include <hip/hip_bf16.h>

// Problem constants
#define NB   256
#define NC   4096
#define NF   64
#define NG   512
#define NH   128
#define NELEM (NB*NC)            // 1048576
#define NSEG  (NB*NG + 1)        // 131073
#define LDX  66                  // row stride of x_with_meta in floats
#define NEGV (-1000000000.0f)

typedef __attribute__((ext_vector_type(8))) short short8;
typedef __attribute__((ext_vector_type(4))) float f32x4;

// LDS geometry (ushort units)
#define AS_LD   72    // feats tile 64x64 padded to 72 (row 144B: 16B-aligned, 2-way banks)
#define WS0_LD  72    // W0T 128x72
#define HS_LD   136   // h1 64x128 padded to 136 (row 272B)
#define WS1_LD  136   // W1T 128x136
#define WS0_OFF 4608  // ushort offset of Ws0 inside sR0 (As is 64*72=4608 ushorts)

__device__ __forceinline__ unsigned short f2bf(float f) {
    unsigned u = __float_as_uint(f);
    unsigned r = (u + 0x7FFFu + ((u >> 16) & 1u)) >> 16;
    return (unsigned short)r;
}
__device__ __forceinline__ unsigned encf(float f) {
    unsigned u = __float_as_uint(f);
    return (u & 0x80000000u) ? ~u : (u | 0x80000000u);
}
__device__ __forceinline__ float decf(unsigned u) {
    unsigned v = (u & 0x80000000u) ? (u ^ 0x80000000u) : ~u;
    return __uint_as_float(v);
}

// ---------------- kernel 0: weight prep (fp32 -> bf16, transposed, padded) ----
__global__ void k_prep(const float* __restrict__ W0, const float* __restrict__ W1,
                       unsigned short* __restrict__ W0T, unsigned short* __restrict__ W1T) {
    int i = blockIdx.x * 256 + threadIdx.x;
    if (i < 128 * AS_LD) {                 // W0T[j][k] = W0[k][j], 128x72
        int j = i / WS0_LD, k = i % WS0_LD;
        W0T[i] = (k < NF) ? f2bf(W0[k * NH + j]) : (unsigned short)0;
    } else {
        int i2 = i - 128 * WS0_LD;
        if (i2 < 128 * WS1_LD) {           // W1T[j][k] = W1[k][j], 128x136
            int j = i2 / WS1_LD, k = i2 % WS1_LD;
            W1T[i2] = (k < NH) ? f2bf(W1[k * NH + j]) : (unsigned short)0;
        }
    }
}

// ---------------- kernel 1: fused MLP + segment atomics -----------------------
__global__ __launch_bounds__(256, 2) void k_mlp(
        const float* __restrict__ X, const float* __restrict__ b2p,
        const unsigned short* __restrict__ W0T, const unsigned short* __restrict__ W1T,
        const float* __restrict__ b0, const float* __restrict__ b1,
        const float* __restrict__ W2,
        float* __restrict__ rawOut, float2* __restrict__ meta2,
        unsigned* __restrict__ segCnt, float* __restrict__ segSum,
        unsigned* __restrict__ segMax) {
    // region0: As[64][72] at 0, Ws0[128][72] at 4608; after GEMM1 reused as Hs[64][136]
    __shared__ __align__(16) unsigned short sR0[13824];   // 27648 B
    __shared__ __align__(16) unsigned short sWs1[17408];  // 34816 B
    __shared__ float sB0[128], sB1[128], sW2[128];
    __shared__ __align__(16) float sMeta[128];            // float2[64] (gid,mask)

    const int t  = threadIdx.x;
    const int bb = blockIdx.x;
    const int m0 = bb * 64;

    // ---- stage feats (64 rows x 64 cols -> bf16 LDS) ----
    {
        int r = t >> 2, p = t & 3;
        const float* src = X + (size_t)(m0 + r) * LDX + p * 16;
        unsigned pk[8];
#pragma unroll
        for (int i = 0; i < 8; ++i) {
            float2 v = *(const float2*)(src + 2 * i);
            pk[i] = (unsigned)f2bf(v.x) | ((unsigned)f2bf(v.y) << 16);
        }
        unsigned* dst = (unsigned*)(sR0 + r * AS_LD + p * 16);
        ((uint4*)dst)[0] = make_uint4(pk[0], pk[1], pk[2], pk[3]);
        ((uint4*)dst)[1] = make_uint4(pk[4], pk[5], pk[6], pk[7]);
    }
    if (t < 64) {  // meta (gid,mask) at cols 64,65
        float2 mv = *(const float2*)(X + (size_t)(m0 + t) * LDX + 64);
        ((float2*)sMeta)[t] = mv;
    }
    if (t < 128) { sB0[t] = b0[t]; sB1[t] = b1[t]; sW2[t] = W2[t]; }
    // ---- stage weights (pre-converted, same linear layout) ----
    {
        const uint4* s0 = (const uint4*)W0T;
        uint4* d0 = (uint4*)(sR0 + WS0_OFF);
#pragma unroll
        for (int i = 0; i < 5; ++i) { int c = i * 256 + t; if (c < 1152) d0[c] = s0[c]; }
        const uint4* s1 = (const uint4*)W1T;
        uint4* d1 = (uint4*)sWs1;
#pragma unroll
        for (int i = 0; i < 9; ++i) { int c = i * 256 + t; if (c < 2176) d1[c] = s1[c]; }
    }
    __syncthreads();

    const int l = t & 63, w = t >> 6;
    const int l15 = l & 15, g = l >> 4;

    // ---- GEMM1: h1 = feats @ W0 ----
    f32x4 acc[8];
#pragma unroll
    for (int n = 0; n < 8; ++n) acc[n] = (f32x4){0.f, 0.f, 0.f, 0.f};
    {
        short8 a0 = *(const short8*)(sR0 + (w * 16 + l15) * AS_LD + g * 8);
        short8 a1 = *(const short8*)(sR0 + (w * 16 + l15) * AS_LD + 32 + g * 8);
#pragma unroll
        for (int n = 0; n < 8; ++n) {
            short8 bf0 = *(const short8*)(sR0 + WS0_OFF + (n * 16 + l15) * WS0_LD + g * 8);
            short8 bf1 = *(const short8*)(sR0 + WS0_OFF + (n * 16 + l15) * WS0_LD + 32 + g * 8);
            acc[n] = __builtin_amdgcn_mfma_f32_16x16x32_bf16(a0, bf0, acc[n], 0, 0, 0);
            acc[n] = __builtin_amdgcn_mfma_f32_16x16x32_bf16(a1, bf1, acc[n], 0, 0, 0);
        }
    }
    __syncthreads();   // all GEMM1 LDS reads consumed -> safe to overwrite region0

    // ---- relu + bias, bf16, write h1 to Hs (over As/Ws0) ----
#pragma unroll
    for (int n = 0; n < 8; ++n) {
        int col = n * 16 + l15;
        float bv = sB0[col];
#pragma unroll
        for (int q = 0; q < 4; ++q) {
            float h = fmaxf(acc[n][q] + bv, 0.f);
            int row = w * 16 + g * 4 + q;
            sR0[row * HS_LD + col] = f2bf(h);
        }
    }
    __syncthreads();

    // ---- GEMM2: h2 = h1 @ W1 ----
    f32x4 acc2[8];
#pragma unroll
    for (int n = 0; n < 8; ++n) acc2[n] = (f32x4){0.f, 0.f, 0.f, 0.f};
    short8 af[4];
#pragma unroll
    for (int k4 = 0; k4 < 4; ++k4)
        af[k4] = *(const short8*)(sR0 + (w * 16 + l15) * HS_LD + k4 * 32 + g * 8);
#pragma unroll
    for (int n = 0; n < 8; ++n) {
#pragma unroll
        for (int k4 = 0; k4 < 4; ++k4) {
            short8 bf = *(const short8*)(sWs1 + (n * 16 + l15) * WS1_LD + k4 * 32 + g * 8);
            acc2[n] = __builtin_amdgcn_mfma_f32_16x16x32_bf16(af[k4], bf, acc2[n], 0, 0, 0);
        }
    }

    // ---- epilogue: relu, dot with W2, 16-lane reduce ----
    float rq[4] = {0.f, 0.f, 0.f, 0.f};
#pragma unroll
    for (int n = 0; n < 8; ++n) {
        int col = n * 16 + l15;
        float b1v = sB1[col], w2v = sW2[col];
#pragma unroll
        for (int q = 0; q < 4; ++q) {
            float h = fmaxf(acc2[n][q] + b1v, 0.f);
            rq[q] += h * w2v;
        }
    }
#pragma unroll
    for (int off = 1; off < 16; off <<= 1) {
#pragma unroll
        for (int q = 0; q < 4; ++q) rq[q] += __shfl_xor(rq[q], off, 64);
    }
    if (l15 == 0) {
        float b2v = b2p[0];
#pragma unroll
        for (int q = 0; q < 4; ++q) {
            int row = w * 16 + g * 4 + q;
            size_t m = (size_t)m0 + row;
            float rv = rq[q] + b2v;
            rawOut[m] = rv;
            float2 mt = ((float2*)sMeta)[row];
            meta2[m] = mt;
            int gid = (int)mt.x;
            if (mt.y > 0.f && gid >= 0) {
                int seg = (int)(m >> 12) * NG + gid;
                atomicAdd(&segCnt[seg], 1u);
                atomicAdd(&segSum[seg], rv);
                atomicMax(&segMax[seg], encf(rv));
            }
        }
    }
}

// ---------------- kernel 2: per-segment stats + bias MLP ----------------------
__global__ void k_seg(const unsigned* __restrict__ cnt, const float* __restrict__ sum,
                      const unsigned* __restrict__ mx,
                      const float* __restrict__ Wb0, const float* __restrict__ bb0,
                      const float* __restrict__ Wb1, const float* __restrict__ bb1,
                      float4* __restrict__ segstats) {
    int s = blockIdx.x * 256 + threadIdx.x;
    if (s >= NSEG) return;
    unsigned c = cnt[s];
    float smax = (c > 0) ? decf(mx[s]) : 0.f;
    float mean = sum[s] / fmaxf((float)c, 1.f);
    float multi = (c > 1) ? 1.f : 0.f;
    float bias = 0.f;
    if (c > 1) {
        float s0 = smax, s1 = mean, s2 = (float)c;
        bias = bb1[0];
#pragma unroll
        for (int j = 0; j < 32; ++j) {
            float h = s0 * Wb0[j] + s1 * Wb0[32 + j] + s2 * Wb0[64 + j] + bb0[j];
            bias += fmaxf(h, 0.f) * Wb1[j];
        }
    }
    segstats[s] = make_float4(smax, mean, bias, multi);
}

// ---------------- kernel 3: gather + fair/mask writeout -----------------------
__global__ void k_final(const float* __restrict__ raw, const float2* __restrict__ meta2,
                        const float4* __restrict__ segstats, float* __restrict__ out) {
    size_t m = (size_t)blockIdx.x * 256 + threadIdx.x;
    float rv = raw[m];
    float2 mt = meta2[m];
    int gid = (int)mt.x;
    float fair;
    if (mt.y > 0.f) {
        fair = rv;
        if (gid >= 0) {
            int seg = (int)(m >> 12) * NG + gid;
            float4 st = segstats[seg];
            if (st.w > 0.5f) fair = 1.5f * rv - st.y + 0.5f * st.x + st.z;
        }
    } else {
        fair = NEGV;
    }
    out[m] = fair;
    out[NELEM + m] = mt.y;
}

// ---------------- launch ------------------------------------------------------
extern "C" void kernel_launch(void* const* d_in, const int* in_sizes, int n_in,
                              void* d_out, int out_size, void* d_ws, size_t ws_size,
                              hipStream_t stream) {
    const float* X   = (const float*)d_in[0];
    const float* W0  = (const float*)d_in[1];
    const float* b0  = (const float*)d_in[2];
    const float* W1  = (const float*)d_in[3];
    const float* b1  = (const float*)d_in[4];
    const float* W2  = (const float*)d_in[5];
    const float* b2  = (const float*)d_in[6];
    const float* Wb0 = (const float*)d_in[7];
    const float* bb0 = (const float*)d_in[8];
    const float* Wb1 = (const float*)d_in[9];
    const float* bb1 = (const float*)d_in[10];

    char* ws = (char*)d_ws;
    // ws layout (bytes)
    float*          raw      = (float*)(ws + 0);                 //  4 MB
    float2*         meta2    = (float2*)(ws + 4194304);          //  8 MB
    float4*         segstats = (float4*)(ws + 12582912);         //  2 MB
    unsigned*       cnt      = (unsigned*)(ws + 14680080);
    float*          sum      = (float*)(ws + 15204372);
    unsigned*       mx       = (unsigned*)(ws + 15728664);
    unsigned short* W0T      = (unsigned short*)(ws + 16252960); // 18432 B
    unsigned short* W1T      = (unsigned short*)(ws + 16271392); // 34816 B

    hipMemsetAsync(ws + 14680080, 0, 3u * 524292u, stream);      // cnt+sum+mx
    k_prep<<<104, 256, 0, stream>>>(W0, W1, W0T, W1T);
    k_mlp<<<NELEM / 64, 256, 0, stream>>>(X, b2, W0T, W1T, b0, b1, W2,
                                          raw, meta2, cnt, sum, mx);
    k_seg<<<(NSEG + 255) / 256, 256, 0, stream>>>(cnt, sum, mx, Wb0, bb0, Wb1, bb1, segstats);
    k_final<<<NELEM / 256, 256, 0, stream>>>(raw, meta2, segstats, (float*)d_out);
}